// Round 1
// baseline (236.041 us; speedup 1.0000x reference)
//
#include <hip/hip_runtime.h>

typedef __bf16 bf16;
typedef __bf16 bf16x8 __attribute__((ext_vector_type(8)));
typedef float f32x4 __attribute__((ext_vector_type(4)));

#define M_TOT 4096
#define D_IN  784
#define HALF  392
#define MID   1000
#define K0PAD 416   // 392 padded to mult of 32
#define NPAD  1024  // 1000 padded
#define N5PAD 512   // 392 padded to mult of 128

// ---------- async global->LDS 16B helper ----------
__device__ __forceinline__ void g2l16(const bf16* g, bf16* l) {
  __builtin_amdgcn_global_load_lds(
      (__attribute__((address_space(1))) void*)(g),
      (__attribute__((address_space(3))) void*)(l),
      16, 0, 0);
}

// ---------- pack first = x[:,0::2] -> bf16, pad K to 416 ----------
__global__ void pack_first_k(const float* __restrict__ x, bf16* __restrict__ A0) {
  int k = blockIdx.x * 256 + threadIdx.x;
  int m = blockIdx.y;
  if (k < K0PAD) {
    A0[(size_t)m * K0PAD + k] =
        (k < HALF) ? (bf16)x[(size_t)m * D_IN + 2 * k] : (bf16)0.f;
  }
}

// ---------- transpose fp32 (K x N) -> bf16 (Npad x Kpad), zero-padded ----------
__global__ void transpose_w_k(const float* __restrict__ W, bf16* __restrict__ WT,
                              int K, int N, int Kpad, int Npad) {
  __shared__ float t[32][33];
  int n0 = blockIdx.x * 32, k0 = blockIdx.y * 32;
  int tx = threadIdx.x, ty = threadIdx.y;  // block (32,8)
#pragma unroll
  for (int r = 0; r < 4; ++r) {
    int k = k0 + ty + 8 * r, n = n0 + tx;
    t[ty + 8 * r][tx] = (k < K && n < N) ? W[(size_t)k * N + n] : 0.f;
  }
  __syncthreads();
#pragma unroll
  for (int r = 0; r < 4; ++r) {
    int n = n0 + ty + 8 * r, k = k0 + tx;
    if (n < Npad && k < Kpad) WT[(size_t)n * Kpad + k] = (bf16)t[tx][ty + 8 * r];
  }
}

// ---------- GEMM: C = relu(A @ BT^T + bias), A:(4096 x K) bf16, BT:(Npad x K) bf16
// 128x128 tile, BK=32, 4 waves, mfma_f32_16x16x32_bf16, m97-style staging ----------
__global__ __launch_bounds__(256, 1)
void gemm_relu_k(const bf16* __restrict__ A, const bf16* __restrict__ BT,
                 const float* __restrict__ bias, int bias_n,
                 bf16* __restrict__ C, int K) {
  __shared__ bf16 ldsA[128 * 32];
  __shared__ bf16 ldsB[128 * 32];
  const int tid = threadIdx.x;
  const int wave = tid >> 6, lane = tid & 63;
  const int bn = blockIdx.x, bm = blockIdx.y;

  // staging: each wave stages 32 rows of A-tile and B-tile (2 x 1KB instr each)
  const size_t arow = (size_t)bm * 128 + wave * 32 + (lane >> 2);
  const size_t brow = (size_t)bn * 128 + wave * 32 + (lane >> 2);
  const int kcol = (lane & 3) * 8;
  const bf16* ga0 = A + arow * K + kcol;
  const bf16* ga1 = ga0 + (size_t)16 * K;
  const bf16* gb0 = BT + brow * K + kcol;
  const bf16* gb1 = gb0 + (size_t)16 * K;
  bf16* la0 = &ldsA[(wave * 32) * 32];
  bf16* la1 = &ldsA[(wave * 32 + 16) * 32];
  bf16* lb0 = &ldsB[(wave * 32) * 32];
  bf16* lb1 = &ldsB[(wave * 32 + 16) * 32];

  const int mlane = lane & 15, quad = lane >> 4;
  const int wm = (wave & 1) * 64, wn = (wave >> 1) * 64;
  const bf16* ra = &ldsA[(wm + mlane) * 32 + quad * 8];
  const bf16* rb = &ldsB[(wn + mlane) * 32 + quad * 8];

  f32x4 acc[4][4] = {};

  // stage tile 0
  g2l16(ga0, la0); g2l16(ga1, la1); g2l16(gb0, lb0); g2l16(gb1, lb1);

  const int KT = K >> 5;
  for (int kt = 0; kt < KT; ++kt) {
    __syncthreads();  // staging of tile kt complete
    bf16x8 af[4], bfr[4];
#pragma unroll
    for (int i = 0; i < 4; ++i) af[i] = *(const bf16x8*)(ra + i * 512);
#pragma unroll
    for (int i = 0; i < 4; ++i) bfr[i] = *(const bf16x8*)(rb + i * 512);
    __syncthreads();  // all waves done reading LDS
    if (kt + 1 < KT) {
      const size_t off = (size_t)(kt + 1) * 32;
      g2l16(ga0 + off, la0); g2l16(ga1 + off, la1);
      g2l16(gb0 + off, lb0); g2l16(gb1 + off, lb1);
    }
#pragma unroll
    for (int mt = 0; mt < 4; ++mt)
#pragma unroll
      for (int nt = 0; nt < 4; ++nt)
        acc[mt][nt] = __builtin_amdgcn_mfma_f32_16x16x32_bf16(
            af[mt], bfr[nt], acc[mt][nt], 0, 0, 0);
  }

  // epilogue: bias + relu, store bf16 (C stride NPAD)
  const int ng0 = bn * 128 + wn + mlane;
  const int mg0 = bm * 128 + wm + quad * 4;
  float bv[4];
#pragma unroll
  for (int nt = 0; nt < 4; ++nt) {
    int n = ng0 + nt * 16;
    bv[nt] = (n < bias_n) ? bias[n] : 0.f;
  }
#pragma unroll
  for (int mt = 0; mt < 4; ++mt)
#pragma unroll
    for (int nt = 0; nt < 4; ++nt)
#pragma unroll
      for (int r = 0; r < 4; ++r) {
        int m = mg0 + mt * 16 + r;
        int n = ng0 + nt * 16;
        float v = acc[mt][nt][r] + bv[nt];
        v = fmaxf(v, 0.f);
        C[(size_t)m * NPAD + n] = (bf16)v;
      }
}

// ---------- final GEMM: y[:,1::2] = A @ W_out + b_out + x[:,1::2] ----------
__global__ __launch_bounds__(256, 1)
void gemm_final_k(const bf16* __restrict__ A, const bf16* __restrict__ BT,
                  const float* __restrict__ b_out, const float* __restrict__ x,
                  float* __restrict__ y, int K) {
  __shared__ bf16 ldsA[128 * 32];
  __shared__ bf16 ldsB[128 * 32];
  const int tid = threadIdx.x;
  const int wave = tid >> 6, lane = tid & 63;
  const int bn = blockIdx.x, bm = blockIdx.y;

  const size_t arow = (size_t)bm * 128 + wave * 32 + (lane >> 2);
  const size_t brow = (size_t)bn * 128 + wave * 32 + (lane >> 2);
  const int kcol = (lane & 3) * 8;
  const bf16* ga0 = A + arow * K + kcol;
  const bf16* ga1 = ga0 + (size_t)16 * K;
  const bf16* gb0 = BT + brow * K + kcol;
  const bf16* gb1 = gb0 + (size_t)16 * K;
  bf16* la0 = &ldsA[(wave * 32) * 32];
  bf16* la1 = &ldsA[(wave * 32 + 16) * 32];
  bf16* lb0 = &ldsB[(wave * 32) * 32];
  bf16* lb1 = &ldsB[(wave * 32 + 16) * 32];

  const int mlane = lane & 15, quad = lane >> 4;
  const int wm = (wave & 1) * 64, wn = (wave >> 1) * 64;
  const bf16* ra = &ldsA[(wm + mlane) * 32 + quad * 8];
  const bf16* rb = &ldsB[(wn + mlane) * 32 + quad * 8];

  f32x4 acc[4][4] = {};
  g2l16(ga0, la0); g2l16(ga1, la1); g2l16(gb0, lb0); g2l16(gb1, lb1);

  const int KT = K >> 5;
  for (int kt = 0; kt < KT; ++kt) {
    __syncthreads();
    bf16x8 af[4], bfr[4];
#pragma unroll
    for (int i = 0; i < 4; ++i) af[i] = *(const bf16x8*)(ra + i * 512);
#pragma unroll
    for (int i = 0; i < 4; ++i) bfr[i] = *(const bf16x8*)(rb + i * 512);
    __syncthreads();
    if (kt + 1 < KT) {
      const size_t off = (size_t)(kt + 1) * 32;
      g2l16(ga0 + off, la0); g2l16(ga1 + off, la1);
      g2l16(gb0 + off, lb0); g2l16(gb1 + off, lb1);
    }
#pragma unroll
    for (int mt = 0; mt < 4; ++mt)
#pragma unroll
      for (int nt = 0; nt < 4; ++nt)
        acc[mt][nt] = __builtin_amdgcn_mfma_f32_16x16x32_bf16(
            af[mt], bfr[nt], acc[mt][nt], 0, 0, 0);
  }

  // epilogue: shift + b_out + second, scatter into interleaved y (odd cols)
  const int ng0 = bn * 128 + wn + mlane;
  const int mg0 = bm * 128 + wm + quad * 4;
#pragma unroll
  for (int nt = 0; nt < 4; ++nt) {
    int n = ng0 + nt * 16;
    if (n < HALF) {
      float bb = b_out[n];
#pragma unroll
      for (int mt = 0; mt < 4; ++mt)
#pragma unroll
        for (int r = 0; r < 4; ++r) {
          int m = mg0 + mt * 16 + r;
          size_t off = (size_t)m * D_IN + 2 * n + 1;
          y[off] = acc[mt][nt][r] + bb + x[off];
        }
    }
  }
}

extern "C" void kernel_launch(void* const* d_in, const int* in_sizes, int n_in,
                              void* d_out, int out_size, void* d_ws, size_t ws_size,
                              hipStream_t stream) {
  const float* x     = (const float*)d_in[0];
  const float* ldj   = (const float*)d_in[1];
  const float* W_in  = (const float*)d_in[2];
  const float* b_in  = (const float*)d_in[3];
  const float* W_hid = (const float*)d_in[4];
  const float* b_hid = (const float*)d_in[5];
  const float* W_out = (const float*)d_in[6];
  const float* b_out = (const float*)d_in[7];
  float* y = (float*)d_out;

  // workspace layout (all offsets 256B-aligned)
  char* p = (char*)d_ws;
  bf16* A0  = (bf16*)p;                         // 4096 x 416
  bf16* H0  = (bf16*)(p + 3407872);             // 4096 x 1024
  bf16* H1  = (bf16*)(p + 3407872 + 8388608);   // 4096 x 1024
  bf16* WT0 = (bf16*)(p + 3407872 + 2 * 8388608);             // 1024 x 416
  bf16* WTh = (bf16*)(p + 3407872 + 2 * 8388608 + 851968);    // 4 x 1024 x 1024
  bf16* WT5 = (bf16*)(p + 3407872 + 3 * 8388608 + 851968);    // 512 x 1024

  // --- pack + weight conversion ---
  pack_first_k<<<dim3(2, M_TOT), 256, 0, stream>>>(x, A0);
  transpose_w_k<<<dim3(32, 13), dim3(32, 8), 0, stream>>>(W_in, WT0, HALF, MID, K0PAD, NPAD);
  for (int i = 0; i < 4; ++i)
    transpose_w_k<<<dim3(32, 32), dim3(32, 8), 0, stream>>>(
        W_hid + (size_t)i * MID * MID, WTh + (size_t)i * NPAD * NPAD, MID, MID, NPAD, NPAD);
  transpose_w_k<<<dim3(16, 32), dim3(32, 8), 0, stream>>>(W_out, WT5, MID, HALF, NPAD, N5PAD);

  // --- MLP ---
  gemm_relu_k<<<dim3(8, 32), 256, 0, stream>>>(A0, WT0, b_in, MID, H0, K0PAD);
  gemm_relu_k<<<dim3(8, 32), 256, 0, stream>>>(H0, WTh + 0 * (size_t)NPAD * NPAD, b_hid + 0 * MID, MID, H1, NPAD);
  gemm_relu_k<<<dim3(8, 32), 256, 0, stream>>>(H1, WTh + 1 * (size_t)NPAD * NPAD, b_hid + 1 * MID, MID, H0, NPAD);
  gemm_relu_k<<<dim3(8, 32), 256, 0, stream>>>(H0, WTh + 2 * (size_t)NPAD * NPAD, b_hid + 2 * MID, MID, H1, NPAD);
  gemm_relu_k<<<dim3(8, 32), 256, 0, stream>>>(H1, WTh + 3 * (size_t)NPAD * NPAD, b_hid + 3 * MID, MID, H0, NPAD);

  // even columns of y = x's even columns: copy whole x, odd cols overwritten next
  hipMemcpyAsync(y, x, (size_t)M_TOT * D_IN * sizeof(float), hipMemcpyDeviceToDevice, stream);

  gemm_final_k<<<dim3(4, 32), 256, 0, stream>>>(H0, WT5, b_out, x, y, NPAD);

  // log_det_J passthrough
  hipMemcpyAsync(y + (size_t)M_TOT * D_IN, ldj, sizeof(float), hipMemcpyDeviceToDevice, stream);
}

// Round 2
// 203.907 us; speedup vs baseline: 1.1576x; 1.1576x over previous
//
#include <hip/hip_runtime.h>

typedef __bf16 bf16;
typedef __bf16 bf16x8 __attribute__((ext_vector_type(8)));
typedef float f32x4 __attribute__((ext_vector_type(4)));

#define M_TOT 4096
#define D_IN  784
#define HALF  392
#define MID   1000
#define K0PAD 448   // 392 -> mult of 64
#define NPAD  1024  // 1000 padded
#define N5PAD 512   // 392 -> mult of 128 (final uses BN=64, grid 8x32)

// ---------- async global->LDS 16B ----------
__device__ __forceinline__ void g2l16(const bf16* g, bf16* l) {
  __builtin_amdgcn_global_load_lds(
      (__attribute__((address_space(1))) void*)(g),
      (__attribute__((address_space(3))) void*)(l),
      16, 0, 0);
}

// ---------- pack first = x[:,0::2] -> bf16, pad K to 448 ----------
__global__ void pack_first_k(const float* __restrict__ x, bf16* __restrict__ A0) {
  int k = blockIdx.x * 256 + threadIdx.x;  // 0..511
  int m = blockIdx.y;
  if (k < K0PAD)
    A0[(size_t)m * K0PAD + k] = (k < HALF) ? (bf16)x[(size_t)m * D_IN + 2 * k] : (bf16)0.f;
}

// ---------- all weight transposes fused: fp32 (K x N) -> bf16 (Npad x Kpad) ----------
__global__ void prep_weights_k(const float* __restrict__ W_in,
                               const float* __restrict__ W_hid,
                               const float* __restrict__ W_out,
                               bf16* __restrict__ WT0, bf16* __restrict__ WTh,
                               bf16* __restrict__ WT5) {
  int t = blockIdx.x;
  const float* W; bf16* WT; int K, N, Kpad, tn, tk;
  if (t < 448) {                 // W_in: (392 x 1000) -> (1024 x 448)
    W = W_in; WT = WT0; K = HALF; N = MID; Kpad = K0PAD;
    tn = t & 31; tk = t >> 5;
  } else if (t < 448 + 4096) {   // W_hid[i]: (1000 x 1000) -> (1024 x 1024)
    int u = t - 448; int i = u >> 10; u &= 1023;
    W = W_hid + (size_t)i * MID * MID; WT = WTh + (size_t)i * NPAD * NPAD;
    K = MID; N = MID; Kpad = NPAD;
    tn = u & 31; tk = u >> 5;
  } else {                       // W_out: (1000 x 392) -> (512 x 1024)
    int u = t - 4544;
    W = W_out; WT = WT5; K = MID; N = HALF; Kpad = NPAD;
    tn = u & 15; tk = u >> 4;
  }
  __shared__ float tb[32][33];
  int n0 = tn * 32, k0 = tk * 32;
  int tx = threadIdx.x, ty = threadIdx.y;  // block (32,8)
#pragma unroll
  for (int r = 0; r < 4; ++r) {
    int k = k0 + ty + 8 * r, n = n0 + tx;
    tb[ty + 8 * r][tx] = (k < K && n < N) ? W[(size_t)k * N + n] : 0.f;
  }
  __syncthreads();
#pragma unroll
  for (int r = 0; r < 4; ++r) {
    int n = n0 + ty + 8 * r, k = k0 + tx;
    WT[(size_t)n * Kpad + k] = (bf16)tb[tx][ty + 8 * r];
  }
}

// ---------- GEMM: 128 x BN tile, BK=64, 4 waves, XOR-swizzled LDS ----------
// EPI=0: C = relu(A@BT^T + bias) bf16, stride NPAD.
// EPI=1: y pairs: y[m][2n]=x[m][2n]; y[m][2n+1]=x[m][2n+1]+acc+bias[n]  (n<HALF)
template <int BN, int EPI>
__global__ __launch_bounds__(256, 1)
void gemm_k(const bf16* __restrict__ A, const bf16* __restrict__ BT,
            const float* __restrict__ bias, int bias_n,
            bf16* __restrict__ C,
            const float* __restrict__ x, float* __restrict__ y,
            int K) {
  constexpr int BM = 128, BK = 64;
  constexpr int WN = BN / 2, NT = WN / 16;
  __shared__ bf16 ldsA[BM * BK];
  __shared__ bf16 ldsB[BN * BK];
  const int tid = threadIdx.x, wave = tid >> 6, lane = tid & 63;
  const int bn = blockIdx.x, bm = blockIdx.y;

  // staging: 8 lanes/row (64 cols * 2B = 128B). Global side is XOR-swizzled so
  // LDS[r][cq] = global[r][cq ^ (r&7)]  (cq = 16B col-group index 0..7).
  const int srow = lane >> 3;
  const int sqz = (lane & 7) ^ srow;  // swizzled global col-group
  const bf16* gA = A + ((size_t)bm * BM + wave * (BM / 4) + srow) * K + sqz * 8;
  const bf16* gB = BT + ((size_t)bn * BN + wave * (BN / 4) + srow) * K + sqz * 8;
  bf16* lA = &ldsA[wave * (BM / 4) * BK];
  bf16* lB = &ldsB[wave * (BN / 4) * BK];

  const int mlane = lane & 15, quad = lane >> 4;
  const int wm = (wave & 1) * 64, wn = (wave >> 1) * WN;
  const int axor = mlane & 7;  // (row&7) for all this lane's frag rows
  const bf16* raBase = &ldsA[(wm + mlane) * BK];
  const bf16* rbBase = &ldsB[(wn + mlane) * BK];

  f32x4 acc[4][NT] = {};

  const int KT = K >> 6;
  // stage tile 0
#pragma unroll
  for (int i = 0; i < BM / 32; ++i) g2l16(gA + (size_t)(8 * i) * K, lA + (8 * i) * BK);
#pragma unroll
  for (int i = 0; i < BN / 32; ++i) g2l16(gB + (size_t)(8 * i) * K, lB + (8 * i) * BK);

  for (int kt = 0; kt < KT; ++kt) {
    __syncthreads();  // staging of tile kt complete
    bf16x8 af[2][4], bfr[2][NT];
#pragma unroll
    for (int s = 0; s < 2; ++s) {
      const int co = ((s * 4 + quad) ^ axor) * 8;  // swizzled read col offset
#pragma unroll
      for (int i = 0; i < 4; ++i) af[s][i] = *(const bf16x8*)(raBase + i * 16 * BK + co);
#pragma unroll
      for (int i = 0; i < NT; ++i) bfr[s][i] = *(const bf16x8*)(rbBase + i * 16 * BK + co);
    }
    __syncthreads();  // all waves done reading LDS
    if (kt + 1 < KT) {
      const size_t off = (size_t)(kt + 1) * BK;
#pragma unroll
      for (int i = 0; i < BM / 32; ++i) g2l16(gA + off + (size_t)(8 * i) * K, lA + (8 * i) * BK);
#pragma unroll
      for (int i = 0; i < BN / 32; ++i) g2l16(gB + off + (size_t)(8 * i) * K, lB + (8 * i) * BK);
    }
#pragma unroll
    for (int s = 0; s < 2; ++s)
#pragma unroll
      for (int mt = 0; mt < 4; ++mt)
#pragma unroll
        for (int nt = 0; nt < NT; ++nt)
          acc[mt][nt] = __builtin_amdgcn_mfma_f32_16x16x32_bf16(
              af[s][mt], bfr[s][nt], acc[mt][nt], 0, 0, 0);
  }

  const int ng0 = bn * BN + wn + mlane;
  const int mg0 = bm * BM + wm + quad * 4;

  if (EPI == 0) {
    float bv[NT];
#pragma unroll
    for (int nt = 0; nt < NT; ++nt) {
      int n = ng0 + nt * 16;
      bv[nt] = (n < bias_n) ? bias[n] : 0.f;
    }
#pragma unroll
    for (int mt = 0; mt < 4; ++mt)
#pragma unroll
      for (int nt = 0; nt < NT; ++nt)
#pragma unroll
        for (int r = 0; r < 4; ++r) {
          int m = mg0 + mt * 16 + r;
          int n = ng0 + nt * 16;
          float v = fmaxf(acc[mt][nt][r] + bv[nt], 0.f);
          C[(size_t)m * NPAD + n] = (bf16)v;
        }
  } else {
    const float2* x2 = (const float2*)x;
    float2* y2 = (float2*)y;
#pragma unroll
    for (int nt = 0; nt < NT; ++nt) {
      int n = ng0 + nt * 16;
      if (n < HALF) {
        float bb = bias[n];
#pragma unroll
        for (int mt = 0; mt < 4; ++mt)
#pragma unroll
          for (int r = 0; r < 4; ++r) {
            int m = mg0 + mt * 16 + r;
            size_t off = (size_t)m * (D_IN / 2) + n;
            float2 v = x2[off];
            v.y += acc[mt][nt][r] + bb;
            y2[off] = v;
          }
      }
    }
  }
}

extern "C" void kernel_launch(void* const* d_in, const int* in_sizes, int n_in,
                              void* d_out, int out_size, void* d_ws, size_t ws_size,
                              hipStream_t stream) {
  const float* x     = (const float*)d_in[0];
  const float* ldj   = (const float*)d_in[1];
  const float* W_in  = (const float*)d_in[2];
  const float* b_in  = (const float*)d_in[3];
  const float* W_hid = (const float*)d_in[4];
  const float* b_hid = (const float*)d_in[5];
  const float* W_out = (const float*)d_in[6];
  const float* b_out = (const float*)d_in[7];
  float* y = (float*)d_out;

  // workspace layout (bytes, 256-aligned)
  char* p = (char*)d_ws;
  bf16* A0  = (bf16*)(p + 0);           // 4096 x 448   (3,670,016 B)
  bf16* H0  = (bf16*)(p + 3670016);     // 4096 x 1024  (8,388,608 B)
  bf16* H1  = (bf16*)(p + 12058624);    // 4096 x 1024
  bf16* WT0 = (bf16*)(p + 20447232);    // 1024 x 448   (917,504 B)
  bf16* WTh = (bf16*)(p + 21364736);    // 4 x 1024 x 1024 (8,388,608 B)
  bf16* WT5 = (bf16*)(p + 29753344);    // 512 x 1024   (1,048,576 B)

  // --- prep: 2 launches ---
  pack_first_k<<<dim3(2, M_TOT), 256, 0, stream>>>(x, A0);
  prep_weights_k<<<dim3(5056), dim3(32, 8), 0, stream>>>(W_in, W_hid, W_out, WT0, WTh, WT5);

  // --- MLP: 6 GEMMs ---
  gemm_k<128, 0><<<dim3(8, 32), 256, 0, stream>>>(A0, WT0, b_in, MID, H0, nullptr, nullptr, K0PAD);
  gemm_k<128, 0><<<dim3(8, 32), 256, 0, stream>>>(H0, WTh + 0 * (size_t)NPAD * NPAD, b_hid + 0 * MID, MID, H1, nullptr, nullptr, NPAD);
  gemm_k<128, 0><<<dim3(8, 32), 256, 0, stream>>>(H1, WTh + 1 * (size_t)NPAD * NPAD, b_hid + 1 * MID, MID, H0, nullptr, nullptr, NPAD);
  gemm_k<128, 0><<<dim3(8, 32), 256, 0, stream>>>(H0, WTh + 2 * (size_t)NPAD * NPAD, b_hid + 2 * MID, MID, H1, nullptr, nullptr, NPAD);
  gemm_k<128, 0><<<dim3(8, 32), 256, 0, stream>>>(H1, WTh + 3 * (size_t)NPAD * NPAD, b_hid + 3 * MID, MID, H0, nullptr, nullptr, NPAD);
  // final: writes BOTH interleaved columns (even = copy of x, odd = second + shift)
  gemm_k<64, 1><<<dim3(8, 32), 256, 0, stream>>>(H0, WT5, b_out, HALF, nullptr, x, y, NPAD);

  // log_det_J passthrough
  hipMemcpyAsync(y + (size_t)M_TOT * D_IN, ldj, sizeof(float), hipMemcpyDeviceToDevice, stream);
}

// Round 3
// 183.933 us; speedup vs baseline: 1.2833x; 1.1086x over previous
//
#include <hip/hip_runtime.h>

typedef __bf16 bf16;
typedef __bf16 bf16x8 __attribute__((ext_vector_type(8)));
typedef float f32x4 __attribute__((ext_vector_type(4)));

#define M_TOT 4096
#define D_IN  784
#define HALF  392
#define MID   1000
#define K0PAD 448   // 392 -> mult of 64
#define NPAD  1024  // 1000 padded
#define N5PAD 512   // 392 -> mult of 64 (final BN=64, grid 8x64)

// ---------- async global->LDS 16B ----------
__device__ __forceinline__ void g2l16(const bf16* g, bf16* l) {
  __builtin_amdgcn_global_load_lds(
      (__attribute__((address_space(1))) void*)(g),
      (__attribute__((address_space(3))) void*)(l),
      16, 0, 0);
}

// ---------- fused prep: pack x-even -> A0 (bf16), transpose all weights,
// copy log_det_J. One launch, 256 threads/block. ----------
// blocks [0, 8192): pack (2 blocks per row of 4096)
// blocks [8192, 8192+5056): weight transposes
__global__ void prep_k(const float* __restrict__ x, const float* __restrict__ ldj,
                       const float* __restrict__ W_in, const float* __restrict__ W_hid,
                       const float* __restrict__ W_out,
                       bf16* __restrict__ A0, bf16* __restrict__ WT0,
                       bf16* __restrict__ WTh, bf16* __restrict__ WT5,
                       float* __restrict__ y) {
  int b = blockIdx.x;
  int tid = threadIdx.x;
  if (b == 0 && tid == 0) y[(size_t)M_TOT * D_IN] = ldj[0];

  if (b < 8192) {  // pack
    int m = b >> 1;
    int k = (b & 1) * 256 + tid;
    if (k < K0PAD)
      A0[(size_t)m * K0PAD + k] = (k < HALF) ? (bf16)x[(size_t)m * D_IN + 2 * k] : (bf16)0.f;
    return;
  }
  int t = b - 8192;
  const float* W; bf16* WT; int K, N, Kpad, tn, tk;
  if (t < 448) {                 // W_in: (392 x 1000) -> (1024 x 448)
    W = W_in; WT = WT0; K = HALF; N = MID; Kpad = K0PAD;
    tn = t & 31; tk = t >> 5;    // 32 n-tiles x 14 k-tiles
  } else if (t < 448 + 4096) {   // W_hid[i]: (1000 x 1000) -> (1024 x 1024)
    int u = t - 448; int i = u >> 10; u &= 1023;
    W = W_hid + (size_t)i * MID * MID; WT = WTh + (size_t)i * NPAD * NPAD;
    K = MID; N = MID; Kpad = NPAD;
    tn = u & 31; tk = u >> 5;
  } else {                       // W_out: (1000 x 392) -> (512 x 1024)
    int u = t - 4544;
    W = W_out; WT = WT5; K = MID; N = HALF; Kpad = NPAD;
    tn = u & 15; tk = u >> 4;    // 16 n-tiles x 32 k-tiles
  }
  __shared__ float tb[32][33];
  int n0 = tn * 32, k0 = tk * 32;
  int tx = tid & 31, ty = tid >> 5;
#pragma unroll
  for (int r = 0; r < 4; ++r) {
    int k = k0 + ty + 8 * r, n = n0 + tx;
    tb[ty + 8 * r][tx] = (k < K && n < N) ? W[(size_t)k * N + n] : 0.f;
  }
  __syncthreads();
#pragma unroll
  for (int r = 0; r < 4; ++r) {
    int n = n0 + ty + 8 * r, k = k0 + tx;
    WT[(size_t)n * Kpad + k] = (bf16)tb[tx][ty + 8 * r];
  }
}

// ---------- GEMM: BM x BN tile, BK=64, 4 waves, XOR-swizzled LDS, 2 blocks/CU ----------
// Wave layout: wm=(wave&1)*(BM/2), wn=(wave>>1)*(BN/2); wave tile (BM/2) x (BN/2).
// EPI=0: C = relu(A@BT^T + bias) bf16, stride NPAD.
// EPI=1: y pairs: y[m][2n]=x[m][2n]; y[m][2n+1]=x[m][2n+1]+acc+bias[n]  (n<HALF)
template <int BM, int BN, int EPI, int K>
__global__ __launch_bounds__(256, 2)
void gemm_k(const bf16* __restrict__ A, const bf16* __restrict__ BT,
            const float* __restrict__ bias, int bias_n,
            bf16* __restrict__ C,
            const float* __restrict__ x, float* __restrict__ y) {
  constexpr int BK = 64;
  constexpr int MT = BM / 32, NT = BN / 32;      // frags per wave (m, n)
  constexpr int KT = K / BK;
  __shared__ bf16 ldsA[BM * BK];
  __shared__ bf16 ldsB[BN * BK];
  const int tid = threadIdx.x, wave = tid >> 6, lane = tid & 63;
  const int bn = blockIdx.x, bm = blockIdx.y;

  // staging: 8 lanes/row (64 cols * 2B = 128B); global 16B-group XOR-swizzled by row.
  const int srow = lane >> 3;
  const int sq = (lane & 7) ^ srow;
  const bf16* gA = A + ((size_t)bm * BM + wave * (BM / 4) + srow) * K + sq * 8;
  const bf16* gB = BT + ((size_t)bn * BN + wave * (BN / 4) + srow) * K + sq * 8;
  bf16* lA = &ldsA[wave * (BM / 4) * BK];
  bf16* lB = &ldsB[wave * (BN / 4) * BK];

  const int mlane = lane & 15, quad = lane >> 4;
  const int wm = (wave & 1) * (BM / 2), wn = (wave >> 1) * (BN / 2);
  const int axor = mlane & 7;
  const bf16* raBase = &ldsA[(wm + mlane) * BK];
  const bf16* rbBase = &ldsB[(wn + mlane) * BK];

  f32x4 acc[MT][NT] = {};

  // stage tile 0
#pragma unroll
  for (int i = 0; i < BM / 32; ++i) g2l16(gA + (size_t)(8 * i) * K, lA + (8 * i) * BK);
#pragma unroll
  for (int i = 0; i < BN / 32; ++i) g2l16(gB + (size_t)(8 * i) * K, lB + (8 * i) * BK);

  for (int kt = 0; kt < KT; ++kt) {
    __syncthreads();  // staging of tile kt complete
    bf16x8 af[2][MT], bfr[2][NT];
#pragma unroll
    for (int s = 0; s < 2; ++s) {
      const int co = ((s * 4 + quad) ^ axor) * 8;
#pragma unroll
      for (int i = 0; i < MT; ++i) af[s][i] = *(const bf16x8*)(raBase + i * 16 * BK + co);
#pragma unroll
      for (int i = 0; i < NT; ++i) bfr[s][i] = *(const bf16x8*)(rbBase + i * 16 * BK + co);
    }
    __syncthreads();  // all waves done reading LDS
    if (kt + 1 < KT) {
      const size_t off = (size_t)(kt + 1) * BK;
#pragma unroll
      for (int i = 0; i < BM / 32; ++i) g2l16(gA + off + (size_t)(8 * i) * K, lA + (8 * i) * BK);
#pragma unroll
      for (int i = 0; i < BN / 32; ++i) g2l16(gB + off + (size_t)(8 * i) * K, lB + (8 * i) * BK);
    }
#pragma unroll
    for (int s = 0; s < 2; ++s)
#pragma unroll
      for (int mt = 0; mt < MT; ++mt)
#pragma unroll
        for (int nt = 0; nt < NT; ++nt)
          acc[mt][nt] = __builtin_amdgcn_mfma_f32_16x16x32_bf16(
              af[s][mt], bfr[s][nt], acc[mt][nt], 0, 0, 0);
  }

  const int ng0 = bn * BN + wn + mlane;
  const int mg0 = bm * BM + wm + quad * 4;

  if (EPI == 0) {
    float bv[NT];
#pragma unroll
    for (int nt = 0; nt < NT; ++nt) {
      int n = ng0 + nt * 16;
      bv[nt] = (n < bias_n) ? bias[n] : 0.f;
    }
#pragma unroll
    for (int mt = 0; mt < MT; ++mt)
#pragma unroll
      for (int nt = 0; nt < NT; ++nt)
#pragma unroll
        for (int r = 0; r < 4; ++r) {
          int m = mg0 + mt * 16 + r;
          int n = ng0 + nt * 16;
          float v = fmaxf(acc[mt][nt][r] + bv[nt], 0.f);
          C[(size_t)m * NPAD + n] = (bf16)v;
        }
  } else {
    const float2* x2 = (const float2*)x;
    float2* y2 = (float2*)y;
#pragma unroll
    for (int nt = 0; nt < NT; ++nt) {
      int n = ng0 + nt * 16;
      if (n < HALF) {
        float bb = bias[n];
#pragma unroll
        for (int mt = 0; mt < MT; ++mt)
#pragma unroll
          for (int r = 0; r < 4; ++r) {
            int m = mg0 + mt * 16 + r;
            size_t off = (size_t)m * (D_IN / 2) + n;
            float2 v = x2[off];
            v.y += acc[mt][nt][r] + bb;
            y2[off] = v;
          }
      }
    }
  }
}

extern "C" void kernel_launch(void* const* d_in, const int* in_sizes, int n_in,
                              void* d_out, int out_size, void* d_ws, size_t ws_size,
                              hipStream_t stream) {
  const float* x     = (const float*)d_in[0];
  const float* ldj   = (const float*)d_in[1];
  const float* W_in  = (const float*)d_in[2];
  const float* b_in  = (const float*)d_in[3];
  const float* W_hid = (const float*)d_in[4];
  const float* b_hid = (const float*)d_in[5];
  const float* W_out = (const float*)d_in[6];
  const float* b_out = (const float*)d_in[7];
  float* y = (float*)d_out;

  // workspace layout (bytes, 256-aligned)
  char* p = (char*)d_ws;
  bf16* A0  = (bf16*)(p + 0);           // 4096 x 448   (3,670,016 B)
  bf16* H0  = (bf16*)(p + 3670016);     // 4096 x 1024  (8,388,608 B)
  bf16* H1  = (bf16*)(p + 12058624);    // 4096 x 1024
  bf16* WT0 = (bf16*)(p + 20447232);    // 1024 x 448   (917,504 B)
  bf16* WTh = (bf16*)(p + 21364736);    // 4 x 1024 x 1024 (8,388,608 B)
  bf16* WT5 = (bf16*)(p + 29753344);    // 512 x 1024   (1,048,576 B)

  // --- prep: 1 launch (pack + all transposes + ldj) ---
  prep_k<<<dim3(8192 + 5056), 256, 0, stream>>>(x, ldj, W_in, W_hid, W_out,
                                                A0, WT0, WTh, WT5, y);

  // --- MLP: 6 GEMMs, 512 blocks each (2 blocks/CU) ---
  gemm_k<64, 128, 0, K0PAD><<<dim3(8, 64), 256, 0, stream>>>(A0, WT0, b_in, MID, H0, nullptr, nullptr);
  gemm_k<64, 128, 0, NPAD><<<dim3(8, 64), 256, 0, stream>>>(H0, WTh + 0 * (size_t)NPAD * NPAD, b_hid + 0 * MID, MID, H1, nullptr, nullptr);
  gemm_k<64, 128, 0, NPAD><<<dim3(8, 64), 256, 0, stream>>>(H1, WTh + 1 * (size_t)NPAD * NPAD, b_hid + 1 * MID, MID, H0, nullptr, nullptr);
  gemm_k<64, 128, 0, NPAD><<<dim3(8, 64), 256, 0, stream>>>(H0, WTh + 2 * (size_t)NPAD * NPAD, b_hid + 2 * MID, MID, H1, nullptr, nullptr);
  gemm_k<64, 128, 0, NPAD><<<dim3(8, 64), 256, 0, stream>>>(H1, WTh + 3 * (size_t)NPAD * NPAD, b_hid + 3 * MID, MID, H0, nullptr, nullptr);
  // final: writes BOTH interleaved columns (even = copy of x, odd = second + shift)
  gemm_k<64, 64, 1, NPAD><<<dim3(8, 64), 256, 0, stream>>>(H0, WT5, b_out, HALF, nullptr, x, y);
}